// Round 3
// baseline (315.094 us; speedup 1.0000x reference)
//
#include <hip/hip_runtime.h>

// Problem constants (B=2, S=2048, D=2048, H=16, DH=128)
#define S_ 2048
#define D_ 2048
#define H_ 16
#define DH_ 128

typedef __attribute__((ext_vector_type(8))) short short8;     // 8 bf16 (4 VGPRs) MFMA frag
typedef __attribute__((ext_vector_type(4))) float f32x4;      // MFMA accumulator
typedef __attribute__((ext_vector_type(8))) unsigned short ushort8;
typedef __attribute__((ext_vector_type(4))) unsigned short ushort4v;

// fp32 -> bf16 bits, round-to-nearest-even
__device__ __forceinline__ unsigned short f2bf(float f) {
  unsigned int u;
  __builtin_memcpy(&u, &f, 4);
  unsigned int lsb = (u >> 16) & 1u;
  u += 0x7fffu + lsb;
  return (unsigned short)(u >> 16);
}

// async global->LDS, 16B per lane; LDS dst = wave-uniform base + lane*16
__device__ __forceinline__ void gload_lds16(const void* g, void* l) {
  __builtin_amdgcn_global_load_lds(
      (const __attribute__((address_space(1))) unsigned int*)g,
      (__attribute__((address_space(3))) unsigned int*)l, 16, 0, 0);
}

// ---------------------------------------------------------------------------
// x (fp32) -> bf16, 8 elems/thread
__global__ void k_convert_x(const float* __restrict__ x, unsigned short* __restrict__ xb) {
  int idx = blockIdx.x * 256 + threadIdx.x;  // 1,048,576 threads
  const float4* xv = (const float4*)x;
  float4 a = xv[(size_t)idx * 2];
  float4 b = xv[(size_t)idx * 2 + 1];
  ushort8 o;
  o[0] = f2bf(a.x); o[1] = f2bf(a.y); o[2] = f2bf(a.z); o[3] = f2bf(a.w);
  o[4] = f2bf(b.x); o[5] = f2bf(b.y); o[6] = f2bf(b.z); o[7] = f2bf(b.w);
  *(ushort8*)(xb + (size_t)idx * 8) = o;
}

// ---------------------------------------------------------------------------
// W [K=2048][Nw] fp32 -> WT [Nw][2048] bf16, with RoPE rotation folded into
// columns n < rot_limit (reference uses constant per-head angles).
__global__ void k_prep_w(const float* __restrict__ W, const float* __restrict__ cosb,
                         const float* __restrict__ sinb, unsigned short* __restrict__ WT,
                         int Nw, int rot_limit) {
  __shared__ float tile[32][129];  // +1 pad: conflict-free column reads
  const int t = threadIdx.x;
  const int kt = blockIdx.x * 32, nt = blockIdx.y * 128;
#pragma unroll
  for (int i = 0; i < 4; ++i) {
    int q = i * 256 + t;            // 1024 float4 loads
    int kl = q >> 5, cq = q & 31;
    float4 v = *(const float4*)(W + (size_t)(kt + kl) * Nw + nt + cq * 4);
    tile[kl][cq * 4 + 0] = v.x; tile[kl][cq * 4 + 1] = v.y;
    tile[kl][cq * 4 + 2] = v.z; tile[kl][cq * 4 + 3] = v.w;
  }
  __syncthreads();
  const bool rot = nt < rot_limit;  // uniform per block
#pragma unroll
  for (int i = 0; i < 16; ++i) {
    int f = i * 256 + t;
    int kl = f & 31, nl = f >> 5;   // nl in [0,128) = dim within head
    int ng = nt + nl;
    float val;
    if (rot) {
      int i0 = nl & 63;
      int h = (ng & 2047) >> 7;
      float c = cosb[h * 64 + i0], sn = sinb[h * 64 + i0];
      float re = tile[kl][i0], im = tile[kl][i0 + 64];
      val = (nl < 64) ? (re * c - im * sn) : (re * sn + im * c);
    } else {
      val = tile[kl][nl];
    }
    WT[(size_t)ng * 2048 + kt + kl] = f2bf(val);
  }
}

// ---------------------------------------------------------------------------
// V [bh][s][128] -> Vt [bh][d][s]  (so PV B-frags read kv-contiguous 16B)
__global__ void k_transpose_v(const unsigned short* __restrict__ V,
                              unsigned short* __restrict__ Vt) {
  __shared__ unsigned short tile[128][72];  // d-major, +8 pad
  const int t = threadIdx.x;
  const int sb = blockIdx.x * 64;
  const int bh = blockIdx.y;
  const unsigned short* Vp = V + (size_t)bh * S_ * DH_;
#pragma unroll
  for (int i = 0; i < 4; ++i) {
    int c8 = i * 256 + t;           // 1024 chunks of 8
    int sl = c8 >> 4, dc = c8 & 15;
    ushort8 v = *(const ushort8*)(Vp + (size_t)(sb + sl) * 128 + dc * 8);
#pragma unroll
    for (int j = 0; j < 8; ++j) tile[dc * 8 + j][sl] = v[j];
  }
  __syncthreads();
  unsigned short* Vtp = Vt + (size_t)bh * DH_ * S_;
#pragma unroll
  for (int i = 0; i < 8; ++i) {
    int q = i * 256 + t;            // 2048 quads
    int d = q >> 4, sq = q & 15;
    ushort4v o;
#pragma unroll
    for (int j = 0; j < 4; ++j) o[j] = tile[d][sq * 4 + j];
    *(ushort4v*)(Vtp + (size_t)d * S_ + sb + sq * 4) = o;
  }
}

// ---------------------------------------------------------------------------
// Deep-pipelined GEMM (T3+T4): C[MxN] = A[M][2048] * Bt[N][2048]^T.
// BN=256 cols, BM=MREP*32 rows, BK=32, 8 waves (2x4), 512 threads.
// 4-slot LDS ring, depth-3 prefetch, ONE counted vmcnt + ONE barrier per
// K-tile (never vmcnt 0 in steady state). Per-row 4-slot swizzle
// pos = s ^ ((row + row/4) & 3): ds_read_b128 2-way (free), staging keeps
// 64B-contiguous rows. Swizzle on SOURCE + READ, linear LDS dest (rule #21).
// MODE 0: scatter Q/K/V head-major bf16 (+bias, Q pre-scaled 1/sqrt(DH)).
// MODE 1: fp32 out (+bias).
template <int MREP, int NCOLS, int MODE>
__global__ __launch_bounds__(512, 2) void k_gemm256(
    const unsigned short* __restrict__ A, const unsigned short* __restrict__ Bt,
    const float* __restrict__ bias,
    unsigned short* __restrict__ Qb, unsigned short* __restrict__ Kb,
    unsigned short* __restrict__ Vb, float* __restrict__ Co) {
  constexpr int BM = MREP * 32;            // 256 or 128
  constexpr int MTILES = 4096 / BM;
  constexpr int NWG = MTILES * (NCOLS / 256);
  constexpr int ABYTES = BM * 64;          // A tile bytes (BM x 32 bf16)
  constexpr int SLOT = ABYTES + 16384;     // + B tile (256 x 32 bf16)
  constexpr int ACH = (BM / 16 + 7) / 8;   // A chunks per wave (2 or 1)
  constexpr int NT = 64;                   // K-tiles: 2048/32
  __shared__ unsigned char lds[4 * SLOT];

  const int tid = threadIdx.x, l = tid & 63, w = tid >> 6;
  const int wm = w >> 2, wn = w & 3;
  // XCD-aware swizzle (bijective: NWG % 8 == 0)
  int bid = blockIdx.x;
  int swz = (bid & 7) * (NWG / 8) + (bid >> 3);
  const int tm = (swz % MTILES) * BM;
  const int tn = (swz / MTILES) * 256;

  // Stage source pointers (per-lane, pre-swizzled) + wave-uniform LDS dests.
  // Chunk = 16 rows x 64B; lane l -> row c*16 + (l>>2), slotpos l&3.
  const unsigned short* asrc[ACH];
  int adst[ACH];
#pragma unroll
  for (int i = 0; i < ACH; ++i) {
    int c = w + i * 8;
    int row = c * 16 + (l >> 2);
    int s = (l & 3) ^ ((row + (row >> 2)) & 3);   // logical slot at this pos
    asrc[i] = A + (size_t)(tm + row) * 2048 + s * 8;
    adst[i] = c * 1024;
  }
  const unsigned short* bsrc[2];
  int bdst[2];
#pragma unroll
  for (int i = 0; i < 2; ++i) {
    int c = w + i * 8;
    int row = c * 16 + (l >> 2);
    int s = (l & 3) ^ ((row + (row >> 2)) & 3);
    bsrc[i] = Bt + (size_t)(tn + row) * 2048 + s * 8;
    bdst[i] = ABYTES + c * 1024;
  }

  // Fragment LDS byte offsets (loop-invariant; slot base added per tile)
  int afo[MREP], bfo[4];
#pragma unroll
  for (int m = 0; m < MREP; ++m) {
    int row = wm * (MREP * 16) + m * 16 + (l & 15);
    afo[m] = row * 64 + (((l >> 4) ^ ((row + (row >> 2)) & 3)) << 4);
  }
#pragma unroll
  for (int n = 0; n < 4; ++n) {
    int row = wn * 64 + n * 16 + (l & 15);
    bfo[n] = ABYTES + row * 64 + (((l >> 4) ^ ((row + (row >> 2)) & 3)) << 4);
  }

  f32x4 acc[MREP][4] = {};

#define STAGE_(u_)                                                     \
  {                                                                    \
    int sb_ = ((u_) & 3) * SLOT;                                       \
    int ko_ = (u_) * 32;                                               \
    _Pragma("unroll") for (int i_ = 0; i_ < ACH; ++i_)                 \
        gload_lds16(asrc[i_] + ko_, lds + sb_ + adst[i_]);             \
    _Pragma("unroll") for (int i_ = 0; i_ < 2; ++i_)                   \
        gload_lds16(bsrc[i_] + ko_, lds + sb_ + bdst[i_]);             \
  }

#define COMPUTE_(u_)                                                   \
  {                                                                    \
    int sb_ = ((u_) & 3) * SLOT;                                       \
    short8 af_[MREP], bf_[4];                                          \
    _Pragma("unroll") for (int m_ = 0; m_ < MREP; ++m_)                \
        af_[m_] = *(const short8*)(lds + sb_ + afo[m_]);               \
    _Pragma("unroll") for (int n_ = 0; n_ < 4; ++n_)                   \
        bf_[n_] = *(const short8*)(lds + sb_ + bfo[n_]);               \
    __builtin_amdgcn_s_setprio(1);                                     \
    _Pragma("unroll") for (int m_ = 0; m_ < MREP; ++m_)                \
        _Pragma("unroll") for (int n_ = 0; n_ < 4; ++n_)               \
            acc[m_][n_] = __builtin_amdgcn_mfma_f32_16x16x32_bf16(     \
                af_[m_], bf_[n_], acc[m_][n_], 0, 0, 0);               \
    __builtin_amdgcn_s_setprio(0);                                     \
  }

  STAGE_(0); STAGE_(1); STAGE_(2);   // depth-3 prologue

#pragma unroll 1
  for (int t = 0; t < NT - 2; ++t) {
    // wait: tile t landed; tiles t+1,t+2 (8 or 6 loads) stay in flight
    if constexpr (MREP == 8) asm volatile("s_waitcnt vmcnt(8)" ::: "memory");
    else                     asm volatile("s_waitcnt vmcnt(6)" ::: "memory");
    asm volatile("s_barrier" ::: "memory");   // all waves: t landed, t-1 reads done
    if (t + 3 < NT) STAGE_(t + 3);            // into slot (t-1)&3 (now free)
    COMPUTE_(t);
  }
  if constexpr (MREP == 8) asm volatile("s_waitcnt vmcnt(4)" ::: "memory");
  else                     asm volatile("s_waitcnt vmcnt(3)" ::: "memory");
  asm volatile("s_barrier" ::: "memory");
  COMPUTE_(NT - 2);
  asm volatile("s_waitcnt vmcnt(0)" ::: "memory");
  asm volatile("s_barrier" ::: "memory");
  COMPUTE_(NT - 1);
#undef STAGE_
#undef COMPUTE_

  // Epilogue. C/D layout: col = lane&15, row = (lane>>4)*4 + reg  [m89]
  const int ln = l & 15, rb4 = (l >> 4) << 2;
#pragma unroll
  for (int m = 0; m < MREP; ++m) {
    int rbase = tm + wm * (MREP * 16) + m * 16 + rb4;
#pragma unroll
    for (int n = 0; n < 4; ++n) {
      int colg = tn + wn * 64 + n * 16 + ln;
      float bv = bias[colg];
#pragma unroll
      for (int j = 0; j < 4; ++j) {
        float v = acc[m][n][j] + bv;
        int r = rbase + j;
        if constexpr (MODE == 0) {
          int reg = colg >> 11;               // 0=q, 1=k, 2=v (uniform/block)
          int b = r >> 11, s = r & 2047;
          int h = (colg & 2047) >> 7, dh = colg & 127;
          size_t off = ((size_t)(b * H_ + h) * S_ + s) * DH_ + dh;
          if (reg == 0) Qb[off] = f2bf(v * 0.08838834764831845f);
          else if (reg == 1) Kb[off] = f2bf(v);
          else Vb[off] = f2bf(v);
        } else {
          Co[(size_t)r * 2048 + colg] = v;
        }
      }
    }
  }
}

// ---------------------------------------------------------------------------
// Causal flash attention, load-balanced + double-buffered staging.
// Grid (pair 0..15, bh 0..31): block handles q-tiles {pair, 31-pair}.
__global__ __launch_bounds__(256) void k_attn(
    const unsigned short* __restrict__ Qb, const unsigned short* __restrict__ Kb,
    const unsigned short* __restrict__ Vt, unsigned short* __restrict__ Ob) {
  __shared__ unsigned short kls[2][8192];   // 2 x 64 rows x 256B (swz)
  __shared__ unsigned short vls[2][8192];   // 2 x 128 rows x 128B (swz)
  __shared__ unsigned short pls[4096];      // 4 waves x [16 x 64] bf16 (swz)
  const int t = threadIdx.x, l = t & 63, w = t >> 6;
  const int pairi = blockIdx.x, bh = blockIdx.y;
  const int b = bh >> 4, h = bh & 15;
  const int rb = (l >> 4) << 2;
  const unsigned short* Qp = Qb + (size_t)bh * S_ * DH_;
  const unsigned short* Kp = Kb + (size_t)bh * S_ * DH_;
  const unsigned short* Vp = Vt + (size_t)bh * DH_ * S_;

#pragma unroll 1
  for (int half = 0; half < 2; ++half) {
    const int qt = half ? (31 - pairi) : pairi;
    const int qb = qt * 64;

    short8 qf[4];
    {
      int row = qb + w * 16 + (l & 15);
#pragma unroll
      for (int c = 0; c < 4; ++c)
        qf[c] = *(const short8*)(Qp + (size_t)row * 128 + c * 32 + ((l >> 4) * 8));
    }

    f32x4 o[8] = {};
    float mrow[4] = {-1e30f, -1e30f, -1e30f, -1e30f};
    float lrow[4] = {0.f, 0.f, 0.f, 0.f};

#pragma unroll
    for (int i = 0; i < 4; ++i) {
      int cid = w + i * 4;  // wave-uniform
      int krow = cid * 4 + (l >> 4);
      int kslot = (l & 15) ^ (krow & 7);
      gload_lds16(Kp + (size_t)krow * 128 + kslot * 8, &kls[0][cid * 512]);
      int vrow = cid * 8 + (l >> 3);
      int vslot = (l & 7) ^ (vrow & 7);
      gload_lds16(Vp + (size_t)vrow * S_ + vslot * 8, &vls[0][cid * 512]);
    }
    __syncthreads();

#pragma unroll 1
    for (int kvt = 0; kvt <= qt; ++kvt) {
      const int kvb = kvt * 64;
      const int cur = kvt & 1;

      if (kvt < qt) {
        const int kvb2 = kvb + 64;
#pragma unroll
        for (int i = 0; i < 4; ++i) {
          int cid = w + i * 4;
          int krow = cid * 4 + (l >> 4);
          int kslot = (l & 15) ^ (krow & 7);
          gload_lds16(Kp + (size_t)(kvb2 + krow) * 128 + kslot * 8,
                      &kls[cur ^ 1][cid * 512]);
          int vrow = cid * 8 + (l >> 3);
          int vslot = (l & 7) ^ (vrow & 7);
          gload_lds16(Vp + (size_t)vrow * S_ + kvb2 + vslot * 8,
                      &vls[cur ^ 1][cid * 512]);
        }
      }

      f32x4 sc[4];
      __builtin_amdgcn_s_setprio(1);
#pragma unroll
      for (int nb = 0; nb < 4; ++nb) {
        f32x4 sacc = {};
#pragma unroll
        for (int c = 0; c < 4; ++c) {
          int row = nb * 16 + (l & 15);
          int off = (c * 64 + ((l >> 4) * 16)) ^ ((row & 7) << 4);
          short8 kf = *(const short8*)((const char*)kls[cur] + row * 256 + off);
          sacc = __builtin_amdgcn_mfma_f32_16x16x32_bf16(qf[c], kf, sacc, 0, 0, 0);
        }
        sc[nb] = sacc;
      }
      __builtin_amdgcn_s_setprio(0);

      float xs[4][4], xm[4];
      const bool diag = (kvt == qt);
#pragma unroll
      for (int j = 0; j < 4; ++j) {
        float m0 = -1e30f;
#pragma unroll
        for (int nb = 0; nb < 4; ++nb) {
          float x = sc[nb][j];
          if (diag) {
            int kv = kvb + nb * 16 + (l & 15);
            if (kv > qb + w * 16 + rb + j) x = -1e30f;  // causal mask
          }
          xs[j][nb] = x;
          m0 = fmaxf(m0, x);
        }
        xm[j] = m0;
      }
#pragma unroll
      for (int msk = 8; msk >= 1; msk >>= 1)
#pragma unroll
        for (int j = 0; j < 4; ++j) xm[j] = fmaxf(xm[j], __shfl_xor(xm[j], msk));

      bool grow = false;
#pragma unroll
      for (int j = 0; j < 4; ++j) grow |= (xm[j] > mrow[j] + 8.f);
      if (__any(grow)) {
        float fsc[4];
#pragma unroll
        for (int j = 0; j < 4; ++j) {
          float nm = fmaxf(mrow[j], xm[j]);
          fsc[j] = __expf(mrow[j] - nm);
          mrow[j] = nm;
        }
#pragma unroll
        for (int d = 0; d < 8; ++d) {
          o[d][0] *= fsc[0]; o[d][1] *= fsc[1]; o[d][2] *= fsc[2]; o[d][3] *= fsc[3];
        }
#pragma unroll
        for (int j = 0; j < 4; ++j) lrow[j] *= fsc[j];
      }
      float rs[4];
#pragma unroll
      for (int j = 0; j < 4; ++j) {
        float s = 0.f;
#pragma unroll
        for (int nb = 0; nb < 4; ++nb) {
          float p = __expf(xs[j][nb] - mrow[j]);
          xs[j][nb] = p;
          s += p;
        }
        rs[j] = s;
      }
#pragma unroll
      for (int msk = 8; msk >= 1; msk >>= 1)
#pragma unroll
        for (int j = 0; j < 4; ++j) rs[j] += __shfl_xor(rs[j], msk);
#pragma unroll
      for (int j = 0; j < 4; ++j) lrow[j] += rs[j];

#pragma unroll
      for (int j = 0; j < 4; ++j) {
        int prow = rb + j;
#pragma unroll
        for (int nb = 0; nb < 4; ++nb) {
          int colb = (nb * 16 + (l & 15)) * 2;
          *(unsigned short*)((char*)pls + w * 2048 + prow * 128 +
                             (colb ^ ((prow & 7) << 4))) = f2bf(xs[j][nb]);
        }
      }
      __syncthreads();

      __builtin_amdgcn_s_setprio(1);
#pragma unroll
      for (int kc = 0; kc < 2; ++kc) {
        int prow = l & 15;
        int poff = (kc * 64 + ((l >> 4) * 16)) ^ ((prow & 7) << 4);
        short8 pa = *(const short8*)((const char*)pls + w * 2048 + prow * 128 + poff);
#pragma unroll
        for (int d = 0; d < 8; ++d) {
          int vrow = d * 16 + (l & 15);
          int voff = (kc * 64 + ((l >> 4) * 16)) ^ ((vrow & 7) << 4);
          short8 vf = *(const short8*)((const char*)vls[cur] + vrow * 128 + voff);
          o[d] = __builtin_amdgcn_mfma_f32_16x16x32_bf16(pa, vf, o[d], 0, 0, 0);
        }
      }
      __builtin_amdgcn_s_setprio(0);
      __syncthreads();
    }

    float inv[4];
#pragma unroll
    for (int j = 0; j < 4; ++j) inv[j] = 1.f / lrow[j];
#pragma unroll
    for (int d = 0; d < 8; ++d) {
#pragma unroll
      for (int j = 0; j < 4; ++j) {
        int s = qb + w * 16 + rb + j;
        int col = h * 128 + d * 16 + (l & 15);
        Ob[((size_t)(b * S_ + s)) * D_ + col] = f2bf(o[d][j] * inv[j]);
      }
    }
  }
}

// ---------------------------------------------------------------------------
extern "C" void kernel_launch(void* const* d_in, const int* in_sizes, int n_in,
                              void* d_out, int out_size, void* d_ws, size_t ws_size,
                              hipStream_t stream) {
  const float* x    = (const float*)d_in[0];
  const float* Wqkv = (const float*)d_in[1];
  const float* bqkv = (const float*)d_in[2];
  const float* Wout = (const float*)d_in[3];
  const float* bout = (const float*)d_in[4];
  const float* fcos = (const float*)d_in[5];
  const float* fsin = (const float*)d_in[6];
  // d_in[7] = mask: causal triu(1), hardcoded in k_attn
  float* out = (float*)d_out;

  // workspace layout (bytes): total 117,440,512
  char* ws = (char*)d_ws;
  unsigned short* xbf   = (unsigned short*)(ws);                       // 16 MB
  unsigned short* wqkvT = (unsigned short*)(ws + 16777216);            // 24 MB
  unsigned short* woutT = (unsigned short*)(ws + 41943040);            //  8 MB
  unsigned short* Qb    = (unsigned short*)(ws + 50331648);            // 16 MB
  unsigned short* Kb    = Qb + 8388608;
  unsigned short* Vb    = Kb + 8388608;
  unsigned short* Vtb   = Vb + 8388608;
  unsigned short* Ob    = xbf;  // alias: xbf dead after GEMM1

  hipLaunchKernelGGL(k_convert_x, dim3(4096), dim3(256), 0, stream, x, xbf);
  hipLaunchKernelGGL(k_prep_w, dim3(64, 48), dim3(256), 0, stream,
                     Wqkv, fcos, fsin, wqkvT, 6144, 4096);
  hipLaunchKernelGGL(k_prep_w, dim3(64, 16), dim3(256), 0, stream,
                     Wout, fcos, fsin, woutT, 2048, 0);
  hipLaunchKernelGGL((k_gemm256<8, 6144, 0>), dim3(384), dim3(512), 0, stream,
                     xbf, wqkvT, bqkv, Qb, Kb, Vb, (float*)nullptr);
  hipLaunchKernelGGL(k_transpose_v, dim3(32, 32), dim3(256), 0, stream, Vb, Vtb);
  hipLaunchKernelGGL(k_attn, dim3(16, 32), dim3(256), 0, stream, Qb, Kb, Vtb, Ob);
  hipLaunchKernelGGL((k_gemm256<4, 2048, 1>), dim3(256), dim3(512), 0, stream,
                     Ob, woutT, bout, (unsigned short*)nullptr,
                     (unsigned short*)nullptr, (unsigned short*)nullptr, out);
}